// Round 2
// baseline (901.398 us; speedup 1.0000x reference)
//
#include <hip/hip_runtime.h>
#include <hip/hip_bf16.h>
#include <math.h>

typedef __attribute__((ext_vector_type(8))) short bf16x8;  // 8 bf16 = 4 VGPR
typedef __attribute__((ext_vector_type(4))) float f32x4;   // MFMA acc

__device__ __forceinline__ float b2f(unsigned short u) {
    union { unsigned int i; float f; } c; c.i = ((unsigned int)u) << 16; return c.f;
}
__device__ __forceinline__ unsigned short f2b(float f) {
    union { float f; unsigned int i; } c; c.f = f;
    unsigned int i = c.i;
    unsigned int r = (i + 0x7fffu + ((i >> 16) & 1u)) >> 16;  // RNE
    return (unsigned short)r;
}
__device__ __forceinline__ void unpack2(unsigned int v, float& lo, float& hi) {
    union { unsigned int i; float f; } c0, c1;
    c0.i = v << 16; c1.i = v & 0xffff0000u;
    lo = c0.f; hi = c1.f;
}
__device__ __forceinline__ uint2 pack4(float4 v) {
    uint2 pk;
    pk.x = (unsigned int)f2b(v.x) | ((unsigned int)f2b(v.y) << 16);
    pk.y = (unsigned int)f2b(v.z) | ((unsigned int)f2b(v.w) << 16);
    return pk;
}

// C[M,N] = A[M,K] @ W[N,K]^T + bias0[n] + bias1[n]
// A, W are f32; converted to bf16 during LDS staging. Up to 4 K-pieces of 512
// columns each, selected by k>>9. stride==0 on an A piece = broadcast row.
// Output: f32 (outF) or bf16 (outB).
template<int BM, int BN, int WM, int WN>
__global__ __launch_bounds__(256, 2)
void gemm_bt(const float* __restrict__ A0, const float* __restrict__ A1,
             const float* __restrict__ A2, const float* __restrict__ A3,
             int as0, int as1, int as2, int as3,
             const float* __restrict__ B0, const float* __restrict__ B1,
             const float* __restrict__ B2, const float* __restrict__ B3,
             int bs0, int bs1, int bs2, int bs3,
             const float* __restrict__ bias0, const float* __restrict__ bias1,
             float* __restrict__ outF, unsigned short* __restrict__ outB,
             int N, int K)
{
    __shared__ __align__(16) unsigned short Alds[BM * 32];
    __shared__ __align__(16) unsigned short Blds[BN * 32];
    const int t = threadIdx.x;
    const int m0 = blockIdx.x * BM;
    const int n0 = blockIdx.y * BN;
    constexpr int WCOLS = BN / WN;
    constexpr int MT = WM / 16, NT = WN / 16;
    const int w = t >> 6, lane = t & 63;
    const int wr = w / WCOLS, wcid = w % WCOLS;
    const int mrow = lane & 15, koff = (lane >> 4) * 8;

    f32x4 acc[MT][NT];
#pragma unroll
    for (int i = 0; i < MT; ++i)
#pragma unroll
        for (int j = 0; j < NT; ++j)
#pragma unroll
            for (int r = 0; r < 4; ++r) acc[i][j][r] = 0.f;

    for (int kt = 0; kt < K; kt += 32) {
        const int p = kt >> 9;
        const float* ap = (p == 0) ? A0 : (p == 1) ? A1 : (p == 2) ? A2 : A3;
        const int astr   = (p == 0) ? as0 : (p == 1) ? as1 : (p == 2) ? as2 : as3;
        const float* bp = (p == 0) ? B0 : (p == 1) ? B1 : (p == 2) ? B2 : B3;
        const int bstr   = (p == 0) ? bs0 : (p == 1) ? bs1 : (p == 2) ? bs2 : bs3;
        const int kin = kt & 511;
        // stage A: each chunk = 4 f32 -> 4 bf16 (8B to LDS)
#pragma unroll
        for (int c = t; c < BM * 8; c += 256) {
            const int row = c >> 3, q = c & 7;
            const float4 v = *(const float4*)(ap + (size_t)(m0 + row) * astr + kin + q * 4);
            *(uint2*)&Alds[row * 32 + q * 4] = pack4(v);
        }
#pragma unroll
        for (int c = t; c < BN * 8; c += 256) {
            const int row = c >> 3, q = c & 7;
            const float4 v = *(const float4*)(bp + (size_t)(n0 + row) * bstr + kin + q * 4);
            *(uint2*)&Blds[row * 32 + q * 4] = pack4(v);
        }
        __syncthreads();
        bf16x8 af[MT], bfr[NT];
#pragma unroll
        for (int i = 0; i < MT; ++i)
            af[i] = *(const bf16x8*)&Alds[(wr * WM + i * 16 + mrow) * 32 + koff];
#pragma unroll
        for (int j = 0; j < NT; ++j)
            bfr[j] = *(const bf16x8*)&Blds[(wcid * WN + j * 16 + mrow) * 32 + koff];
#pragma unroll
        for (int i = 0; i < MT; ++i)
#pragma unroll
            for (int j = 0; j < NT; ++j)
                acc[i][j] = __builtin_amdgcn_mfma_f32_16x16x32_bf16(af[i], bfr[j], acc[i][j], 0, 0, 0);
        __syncthreads();
    }

    const int r0 = (lane >> 4) * 4;
#pragma unroll
    for (int i = 0; i < MT; ++i) {
        const int gm = m0 + wr * WM + i * 16 + r0;
#pragma unroll
        for (int j = 0; j < NT; ++j) {
            const int gn = n0 + wcid * WN + j * 16 + (lane & 15);
            float bs = 0.f;
            if (bias0) bs += bias0[gn];
            if (bias1) bs += bias1[gn];
#pragma unroll
            for (int r = 0; r < 4; ++r) {
                const float v = acc[i][j][r] + bs;
                const size_t off = (size_t)(gm + r) * N + gn;
                if (outF) outF[off] = v;
                else      outB[off] = f2b(v);
            }
        }
    }
}

// pointwise LSTM cell: gates[B,2048] f32 (i,f,g,o) + c_prev f32 -> h,c f32
__global__ __launch_bounds__(256)
void lstm_cell(const float* __restrict__ gates, const float* __restrict__ c_prev,
               float* __restrict__ h_out, float* __restrict__ c_out,
               float* __restrict__ h2_out)
{
    const int idx = blockIdx.x * 256 + threadIdx.x;  // 0..262143
    const int b = idx >> 9, j = idx & 511;
    const float* g = gates + (size_t)b * 2048;
    const float gi = g[j], gf = g[512 + j], gg = g[1024 + j], go = g[1536 + j];
    const float c = c_prev[idx];
    const float si = 1.f / (1.f + __expf(-gi));
    const float sf = 1.f / (1.f + __expf(-gf));
    const float so = 1.f / (1.f + __expf(-go));
    const float cn = sf * c + si * tanhf(gg);
    const float hn = so * tanhf(cn);
    h_out[idx] = hn;
    c_out[idx] = cn;
    if (h2_out) h2_out[idx] = hn;
}

// per-batch block: att_h = h1@wh^T+bh; scores = wa . tanh(att + att_h) + ba;
// masked softmax; att_res = sum_l w_l * clip[b,l,:]
__global__ __launch_bounds__(256)
void att2_kernel(const unsigned short* __restrict__ att, const float* __restrict__ h1,
                 const float* __restrict__ wh, const float* __restrict__ bh,
                 const float* __restrict__ wa, const float* __restrict__ ba,
                 const float* __restrict__ clip, const int* __restrict__ mask,
                 float* __restrict__ att_res)
{
    __shared__ float s_h1[512];
    __shared__ float s_atth[128];
    __shared__ float s_part[256];
    __shared__ float s_wa[128];
    __shared__ float s_sc[256];
    __shared__ float s_red[8];
    const int b = blockIdx.x, t = threadIdx.x;

    s_h1[t]       = h1[(size_t)b * 512 + t];
    s_h1[256 + t] = h1[(size_t)b * 512 + 256 + t];
    if (t < 128) s_wa[t] = wa[t];
    __syncthreads();

    {   // att_h partials: thread t -> (a = t&127, half = t>>7), 256 MACs each
        const int a = t & 127, half = t >> 7;
        const float4* wr4 = (const float4*)(wh + (size_t)a * 512 + half * 256);
        const float* hh = s_h1 + half * 256;
        float s = 0.f;
#pragma unroll 4
        for (int k4 = 0; k4 < 64; ++k4) {
            const float4 vv = wr4[k4];
            const float* hp = hh + k4 * 4;
            s += vv.x * hp[0] + vv.y * hp[1] + vv.z * hp[2] + vv.w * hp[3];
        }
        s_part[t] = s;
    }
    __syncthreads();
    if (t < 128) s_atth[t] = s_part[t] + s_part[128 + t] + bh[t];
    __syncthreads();

    {   // score for l = t  (att is bf16)
        const uint4* ar4 = (const uint4*)(att + ((size_t)b * 256 + t) * 128);
        float s = ba[0];
#pragma unroll 2
        for (int k8 = 0; k8 < 16; ++k8) {
            const uint4 vv = ar4[k8];
            float v0, v1, v2, v3, v4, v5, v6, v7;
            unpack2(vv.x, v0, v1); unpack2(vv.y, v2, v3);
            unpack2(vv.z, v4, v5); unpack2(vv.w, v6, v7);
            const int a0 = k8 * 8;
            s += s_wa[a0 + 0] * tanhf(v0 + s_atth[a0 + 0]);
            s += s_wa[a0 + 1] * tanhf(v1 + s_atth[a0 + 1]);
            s += s_wa[a0 + 2] * tanhf(v2 + s_atth[a0 + 2]);
            s += s_wa[a0 + 3] * tanhf(v3 + s_atth[a0 + 3]);
            s += s_wa[a0 + 4] * tanhf(v4 + s_atth[a0 + 4]);
            s += s_wa[a0 + 5] * tanhf(v5 + s_atth[a0 + 5]);
            s += s_wa[a0 + 6] * tanhf(v6 + s_atth[a0 + 6]);
            s += s_wa[a0 + 7] * tanhf(v7 + s_atth[a0 + 7]);
        }
        s_sc[t] = s;
    }
    __syncthreads();

    // max-reduce (stability)
    float v = s_sc[t];
    for (int off = 32; off > 0; off >>= 1) v = fmaxf(v, __shfl_down(v, off));
    if ((t & 63) == 0) s_red[t >> 6] = v;
    __syncthreads();
    if (t == 0) s_red[4] = fmaxf(fmaxf(s_red[0], s_red[1]), fmaxf(s_red[2], s_red[3]));
    __syncthreads();
    const float mx = s_red[4];
    // masked exp: softmax->mask->renorm == m*e^s / sum(m*e^s)
    const float e = mask[(size_t)b * 256 + t] ? __expf(s_sc[t] - mx) : 0.f;
    float sv = e;
    for (int off = 32; off > 0; off >>= 1) sv += __shfl_down(sv, off);
    if ((t & 63) == 0) s_red[t >> 6] = sv;
    __syncthreads();
    if (t == 0) s_red[5] = s_red[0] + s_red[1] + s_red[2] + s_red[3];
    __syncthreads();
    const float wgt = e / s_red[5];
    __syncthreads();
    s_sc[t] = wgt;
    __syncthreads();

    // att_res[b, 2t..2t+1] = sum_l w_l * clip[b,l,2t..2t+1]; skip masked-out l
    float acc0 = 0.f, acc1 = 0.f;
    const float* cb = clip + (size_t)b * (256 * 512);
    for (int l = 0; l < 256; ++l) {
        const float wl = s_sc[l];
        if (wl != 0.f) {
            const float2 vv = *(const float2*)&cb[l * 512 + 2 * t];
            acc0 += wl * vv.x;
            acc1 += wl * vv.y;
        }
    }
    float2 o; o.x = acc0; o.y = acc1;
    *(float2*)&att_res[(size_t)b * 512 + 2 * t] = o;
}

extern "C" void kernel_launch(void* const* d_in, const int* in_sizes, int n_in,
                              void* d_out, int out_size, void* d_ws, size_t ws_size,
                              hipStream_t stream) {
    typedef const float* cf;
    cf xt      = (cf)d_in[0];
    cf video   = (cf)d_in[1];
    cf event   = (cf)d_in[2];
    cf clip    = (cf)d_in[3];
    const int* mask = (const int*)d_in[4];
    cf state_h = (cf)d_in[5];
    cf state_c = (cf)d_in[6];
    cf w_ih0 = (cf)d_in[7],  w_hh0 = (cf)d_in[8],  b_ih0 = (cf)d_in[9],  b_hh0 = (cf)d_in[10];
    cf w_ih1 = (cf)d_in[11], w_hh1 = (cf)d_in[12], b_ih1 = (cf)d_in[13], b_hh1 = (cf)d_in[14];
    cf w_ih2 = (cf)d_in[15], w_hh2 = (cf)d_in[16], b_ih2 = (cf)d_in[17], b_hh2 = (cf)d_in[18];
    cf wc = (cf)d_in[19], bc = (cf)d_in[20];
    cf wh = (cf)d_in[21], bh = (cf)d_in[22];
    cf wa = (cf)d_in[23], ba = (cf)d_in[24];

    float* out = (float*)d_out;
    const int BH = 512 * 512;                 // 262144
    float* new_h = out + BH;                  // [3,B,H]
    float* new_c = out + 4 * BH;              // [3,B,H]

    float* gates            = (float*)d_ws;                                   // 4 MB
    unsigned short* att     = (unsigned short*)((char*)d_ws + (4u << 20));    // 32 MB bf16
    float* att_res          = (float*)((char*)d_ws + (36u << 20));            // 1 MB

    // ---- att = clip @ wc^T + bc   (independent of LSTM chain) ----
    gemm_bt<128, 128, 64, 64><<<dim3(1024, 1), 256, 0, stream>>>(
        clip, nullptr, nullptr, nullptr, 512, 0, 0, 0,
        wc, nullptr, nullptr, nullptr, 512, 0, 0, 0,
        bc, nullptr, nullptr, att, 128, 512);

    // ---- layer 0: A = [xt | video | state_h2 | state_h0], K=2048 ----
    gemm_bt<64, 64, 32, 32><<<dim3(8, 32), 256, 0, stream>>>(
        xt, video, state_h + 2 * BH, state_h, 512, 0, 512, 512,
        w_ih0, w_ih0 + 512, w_ih0 + 1024, w_hh0, 1536, 1536, 1536, 512,
        b_ih0, b_hh0, gates, nullptr, 2048, 2048);
    lstm_cell<<<1024, 256, 0, stream>>>(gates, state_c, new_h, new_c, nullptr);

    // ---- layer 1: A = [event | h0 | state_h1], K=1536 ----
    gemm_bt<64, 64, 32, 32><<<dim3(8, 32), 256, 0, stream>>>(
        event, new_h, state_h + BH, nullptr, 512, 512, 512, 0,
        w_ih1, w_ih1 + 512, w_hh1, nullptr, 1024, 1024, 512, 0,
        b_ih1, b_hh1, gates, nullptr, 2048, 1536);
    lstm_cell<<<1024, 256, 0, stream>>>(gates, state_c + BH, new_h + BH, new_c + BH, nullptr);

    // ---- attention stage 2 (needs h1) ----
    att2_kernel<<<512, 256, 0, stream>>>(att, new_h + BH, wh, bh, wa, ba, clip, mask, att_res);

    // ---- layer 2: A = [att_res | h1 | state_h2], K=1536 ----
    gemm_bt<64, 64, 32, 32><<<dim3(8, 32), 256, 0, stream>>>(
        att_res, new_h + BH, state_h + 2 * BH, nullptr, 512, 512, 512, 0,
        w_ih2, w_ih2 + 512, w_hh2, nullptr, 1024, 1024, 512, 0,
        b_ih2, b_hh2, gates, nullptr, 2048, 1536);
    lstm_cell<<<1024, 256, 0, stream>>>(gates, state_c + 2 * BH, new_h + 2 * BH, new_c + 2 * BH, out);
}

// Round 3
// 814.567 us; speedup vs baseline: 1.1066x; 1.1066x over previous
//
#include <hip/hip_runtime.h>
#include <math.h>

typedef __attribute__((ext_vector_type(8))) short bf16x8;  // 8 bf16 = 4 VGPR
typedef __attribute__((ext_vector_type(4))) float f32x4;   // MFMA acc

constexpr int LST = 72;  // LDS row stride (shorts) for 64-col bf16 tiles (+8 pad: 144B, 16B-aligned, ~2-way banks)

__device__ __forceinline__ unsigned short f2b(float f) {
    union { float f; unsigned int i; } c; c.f = f;
    unsigned int i = c.i;
    return (unsigned short)((i + 0x7fffu + ((i >> 16) & 1u)) >> 16);  // RNE
}
__device__ __forceinline__ void unpack2(unsigned int v, float& lo, float& hi) {
    union { unsigned int i; float f; } c0, c1;
    c0.i = v << 16; c1.i = v & 0xffff0000u;
    lo = c0.f; hi = c1.f;
}
__device__ __forceinline__ uint2 pack4(float4 v) {
    uint2 pk;
    pk.x = (unsigned int)f2b(v.x) | ((unsigned int)f2b(v.y) << 16);
    pk.y = (unsigned int)f2b(v.z) | ((unsigned int)f2b(v.w) << 16);
    return pk;
}
__device__ __forceinline__ float sigf(float x) { return 1.f / (1.f + __expf(-x)); }
// safe fast tanh: 1 - 2/(1+e^{2x}) -> +-1 at +-inf, no NaN
__device__ __forceinline__ float tanhfast(float x) { return 1.f - 2.f / (1.f + __expf(2.f * x)); }

// ---------------- gate GEMM + fused LSTM cell ----------------
// Computes h,c for one layer: gates = [A-pieces]@[W-pieces]^T + b_ih + b_hh,
// N mapped gate-interleaved: block covers j0..j0+16 for all 4 gates, so each
// lane holds (i,f,g,o) for the same (b,j) and applies the cell in-epilogue.
// NT = threads (128 or 256); BM = NT/4 rows per block; per-wave 16 rows.
template<int NT>
__device__ __forceinline__ void gate_body(
    int bx, int t, unsigned short* Al, unsigned short* Bl,
    const float* __restrict__ A0, const float* __restrict__ A1,
    const float* __restrict__ A2, const float* __restrict__ A3,
    int as0, int as1, int as2, int as3,
    const float* __restrict__ B0, const float* __restrict__ B1,
    const float* __restrict__ B2, const float* __restrict__ B3,
    int bs0, int bs1, int bs2, int bs3,
    const float* __restrict__ b_ih, const float* __restrict__ b_hh,
    const float* __restrict__ c_prev, float* __restrict__ h_out,
    float* __restrict__ c_out, float* __restrict__ h_dup, int K)
{
    constexpr int BM = NT / 4;        // 64 (NT=256) or 32 (NT=128)
    constexpr int MBLK = 512 / BM;
    const int mb = bx % MBLK, jb = bx / MBLK;
    const int m0 = mb * BM, j0 = jb * 16;
    const int w = t >> 6, lane = t & 63;
    const int col = lane & 15, hi = lane >> 4;

    f32x4 acc[4];
#pragma unroll
    for (int g = 0; g < 4; ++g)
#pragma unroll
        for (int r = 0; r < 4; ++r) acc[g][r] = 0.f;

    for (int kt = 0; kt < K; kt += 64) {
        const int p = kt >> 9, kin = kt & 511;
        const float* ap = (p == 0) ? A0 : (p == 1) ? A1 : (p == 2) ? A2 : A3;
        const int astr   = (p == 0) ? as0 : (p == 1) ? as1 : (p == 2) ? as2 : as3;
        const float* bp = (p == 0) ? B0 : (p == 1) ? B1 : (p == 2) ? B2 : B3;
        const int bstr   = (p == 0) ? bs0 : (p == 1) ? bs1 : (p == 2) ? bs2 : bs3;
        // stage A: BM x 64 f32 -> bf16
#pragma unroll
        for (int c = t; c < BM * 16; c += NT) {
            const int row = c >> 4, q = c & 15;
            const float* src = ap + (astr ? (size_t)(m0 + row) * astr : 0) + kin + q * 4;
            *(uint2*)&Al[row * LST + q * 4] = pack4(*(const float4*)src);
        }
        // stage B: 64 rows (4 gates x 16 j) x 64
#pragma unroll
        for (int c = t; c < 1024; c += NT) {
            const int row = c >> 4, q = c & 15;
            const int brow = (row >> 4) * 512 + j0 + (row & 15);
            const float* src = bp + (size_t)brow * bstr + kin + q * 4;
            *(uint2*)&Bl[row * LST + q * 4] = pack4(*(const float4*)src);
        }
        __syncthreads();
#pragma unroll
        for (int sub = 0; sub < 2; ++sub) {
            const int ko = sub * 32 + hi * 8;
            const bf16x8 af = *(const bf16x8*)&Al[(w * 16 + col) * LST + ko];
#pragma unroll
            for (int g = 0; g < 4; ++g) {
                const bf16x8 bfr = *(const bf16x8*)&Bl[(g * 16 + col) * LST + ko];
                acc[g] = __builtin_amdgcn_mfma_f32_16x16x32_bf16(af, bfr, acc[g], 0, 0, 0);
            }
        }
        __syncthreads();
    }
    // epilogue: LSTM cell per lane (rows hi*4+r, col j)
    const int j = j0 + col;
    const float bi = b_ih[j]        + b_hh[j];
    const float bf = b_ih[512 + j]  + b_hh[512 + j];
    const float bg = b_ih[1024 + j] + b_hh[1024 + j];
    const float bo = b_ih[1536 + j] + b_hh[1536 + j];
#pragma unroll
    for (int r = 0; r < 4; ++r) {
        const int bidx = m0 + w * 16 + hi * 4 + r;
        const size_t off = (size_t)bidx * 512 + j;
        const float gi = acc[0][r] + bi, gf = acc[1][r] + bf;
        const float gg = acc[2][r] + bg, go = acc[3][r] + bo;
        const float c = c_prev[off];
        const float cn = sigf(gf) * c + sigf(gi) * tanhfast(gg);
        const float hn = sigf(go) * tanhfast(cn);
        h_out[off] = hn;
        c_out[off] = cn;
        if (h_dup) h_dup[off] = hn;
    }
}

// ---------------- att1: att = clip[131072,512] @ wc[128,512]^T + bc, bf16 out ----------------
__device__ __forceinline__ void att1_body(
    int mb, int t, unsigned short* Al, unsigned short* Bl,
    const float* __restrict__ clip, const float* __restrict__ wc,
    const float* __restrict__ bc, unsigned short* __restrict__ att)
{
    const int m0 = mb * 128;
    const int w = t >> 6, lane = t & 63;
    const int wr = w >> 1, wcid = w & 1;
    const int col = lane & 15, hi = lane >> 4;
    f32x4 acc[4][4];
#pragma unroll
    for (int i = 0; i < 4; ++i)
#pragma unroll
        for (int jx = 0; jx < 4; ++jx)
#pragma unroll
            for (int r = 0; r < 4; ++r) acc[i][jx][r] = 0.f;

    for (int kt = 0; kt < 512; kt += 64) {
#pragma unroll
        for (int c = t; c < 2048; c += 256) {
            const int row = c >> 4, q = c & 15;
            *(uint2*)&Al[row * LST + q * 4] =
                pack4(*(const float4*)(clip + (size_t)(m0 + row) * 512 + kt + q * 4));
        }
#pragma unroll
        for (int c = t; c < 2048; c += 256) {
            const int row = c >> 4, q = c & 15;
            *(uint2*)&Bl[row * LST + q * 4] =
                pack4(*(const float4*)(wc + (size_t)row * 512 + kt + q * 4));
        }
        __syncthreads();
#pragma unroll
        for (int sub = 0; sub < 2; ++sub) {
            const int ko = sub * 32 + hi * 8;
            bf16x8 af[4], bfr[4];
#pragma unroll
            for (int i = 0; i < 4; ++i)
                af[i] = *(const bf16x8*)&Al[(wr * 64 + i * 16 + col) * LST + ko];
#pragma unroll
            for (int jx = 0; jx < 4; ++jx)
                bfr[jx] = *(const bf16x8*)&Bl[(wcid * 64 + jx * 16 + col) * LST + ko];
#pragma unroll
            for (int i = 0; i < 4; ++i)
#pragma unroll
                for (int jx = 0; jx < 4; ++jx)
                    acc[i][jx] = __builtin_amdgcn_mfma_f32_16x16x32_bf16(af[i], bfr[jx], acc[i][jx], 0, 0, 0);
        }
        __syncthreads();
    }
#pragma unroll
    for (int i = 0; i < 4; ++i) {
        const int rb = m0 + wr * 64 + i * 16 + hi * 4;
#pragma unroll
        for (int jx = 0; jx < 4; ++jx) {
            const int n = wcid * 64 + jx * 16 + col;
            const float bias = bc[n];
#pragma unroll
            for (int r = 0; r < 4; ++r)
                att[(size_t)(rb + r) * 128 + n] = f2b(acc[i][jx][r] + bias);
        }
    }
}

// K1: blocks 0..255 = layer0 gemm+cell; blocks 256..1279 = att1
__global__ __launch_bounds__(256, 2)
void k1_fused(const float* xt, const float* video, const float* sh2, const float* sh0,
              const float* w_ih0, const float* w_hh0, const float* b_ih0, const float* b_hh0,
              const float* c_prev0, float* h_out0, float* c_out0,
              const float* clip, const float* wc, const float* bc, unsigned short* att)
{
    __shared__ unsigned short Al[128 * LST];
    __shared__ unsigned short Bl[128 * LST];
    if (blockIdx.x < 256) {
        gate_body<256>(blockIdx.x, threadIdx.x, Al, Bl,
                       xt, video, sh2, sh0, 512, 0, 512, 512,
                       w_ih0, w_ih0 + 512, w_ih0 + 1024, w_hh0, 1536, 1536, 1536, 512,
                       b_ih0, b_hh0, c_prev0, h_out0, c_out0, nullptr, 2048);
    } else {
        att1_body(blockIdx.x - 256, threadIdx.x, Al, Bl, clip, wc, bc, att);
    }
}

// layers 1/2: 128-thread blocks, BM=32, grid 512
__global__ __launch_bounds__(128, 4)
void gate_layer(const float* A0, const float* A1, const float* A2,
                int as0, int as1, int as2,
                const float* w_ih, const float* w_hh,
                const float* b_ih, const float* b_hh,
                const float* c_prev, float* h_out, float* c_out, float* h_dup, int K)
{
    __shared__ unsigned short Al[32 * LST];
    __shared__ unsigned short Bl[64 * LST];
    gate_body<128>(blockIdx.x, threadIdx.x, Al, Bl,
                   A0, A1, A2, nullptr, as0, as1, as2, 0,
                   w_ih, w_ih + 512, w_hh, nullptr, 1024, 1024, 512, 0,
                   b_ih, b_hh, c_prev, h_out, c_out, h_dup, K);
}

// ---------------- att2: scores + masked softmax + weighted clip sum ----------------
__global__ __launch_bounds__(256)
void att2_kernel(const unsigned short* __restrict__ att, const float* __restrict__ h1,
                 const float* __restrict__ wh, const float* __restrict__ bh,
                 const float* __restrict__ wa, const float* __restrict__ ba,
                 const float* __restrict__ clip, const int* __restrict__ mask,
                 float* __restrict__ att_res)
{
    __shared__ float s_h1[512];
    __shared__ float s_atth[128];
    __shared__ float s_part[256];
    __shared__ float s_wa[128];
    __shared__ float s_sc[256];
    __shared__ float s_red[8];
    __shared__ float s_w[256];
    __shared__ int s_idx[256];
    __shared__ int s_cnt;
    const int b = blockIdx.x, t = threadIdx.x;
    if (t == 0) s_cnt = 0;

    s_h1[t]       = h1[(size_t)b * 512 + t];
    s_h1[256 + t] = h1[(size_t)b * 512 + 256 + t];
    if (t < 128) s_wa[t] = wa[t];
    __syncthreads();

    {   // att_h partials
        const int a = t & 127, half = t >> 7;
        const float4* wr4 = (const float4*)(wh + (size_t)a * 512 + half * 256);
        const float* hh = s_h1 + half * 256;
        float s = 0.f;
#pragma unroll 4
        for (int k4 = 0; k4 < 64; ++k4) {
            const float4 vv = wr4[k4];
            const float* hp = hh + k4 * 4;
            s += vv.x * hp[0] + vv.y * hp[1] + vv.z * hp[2] + vv.w * hp[3];
        }
        s_part[t] = s;
    }
    __syncthreads();
    if (t < 128) s_atth[t] = s_part[t] + s_part[128 + t] + bh[t];
    __syncthreads();

    {   // score for l = t
        const uint4* ar4 = (const uint4*)(att + ((size_t)b * 256 + t) * 128);
        float s = ba[0];
#pragma unroll 4
        for (int k8 = 0; k8 < 16; ++k8) {
            const uint4 vv = ar4[k8];
            float v0, v1, v2, v3, v4, v5, v6, v7;
            unpack2(vv.x, v0, v1); unpack2(vv.y, v2, v3);
            unpack2(vv.z, v4, v5); unpack2(vv.w, v6, v7);
            const int a0 = k8 * 8;
            s += s_wa[a0 + 0] * tanhfast(v0 + s_atth[a0 + 0]);
            s += s_wa[a0 + 1] * tanhfast(v1 + s_atth[a0 + 1]);
            s += s_wa[a0 + 2] * tanhfast(v2 + s_atth[a0 + 2]);
            s += s_wa[a0 + 3] * tanhfast(v3 + s_atth[a0 + 3]);
            s += s_wa[a0 + 4] * tanhfast(v4 + s_atth[a0 + 4]);
            s += s_wa[a0 + 5] * tanhfast(v5 + s_atth[a0 + 5]);
            s += s_wa[a0 + 6] * tanhfast(v6 + s_atth[a0 + 6]);
            s += s_wa[a0 + 7] * tanhfast(v7 + s_atth[a0 + 7]);
        }
        s_sc[t] = s;
    }
    __syncthreads();

    float v = s_sc[t];
    for (int off = 32; off > 0; off >>= 1) v = fmaxf(v, __shfl_down(v, off));
    if ((t & 63) == 0) s_red[t >> 6] = v;
    __syncthreads();
    if (t == 0) s_red[4] = fmaxf(fmaxf(s_red[0], s_red[1]), fmaxf(s_red[2], s_red[3]));
    __syncthreads();
    const float mx = s_red[4];
    const float e = mask[(size_t)b * 256 + t] ? __expf(s_sc[t] - mx) : 0.f;
    float sv = e;
    for (int off = 32; off > 0; off >>= 1) sv += __shfl_down(sv, off);
    if ((t & 63) == 0) s_red[t >> 6] = sv;
    __syncthreads();
    if (t == 0) s_red[5] = s_red[0] + s_red[1] + s_red[2] + s_red[3];
    __syncthreads();
    const float wgt = e / s_red[5];
    if (wgt != 0.f) {  // compact active l's (order-free: sum is commutative)
        const int pos = atomicAdd(&s_cnt, 1);
        s_idx[pos] = t;
        s_w[pos] = wgt;
    }
    __syncthreads();
    const int cnt = s_cnt;

    float a0 = 0.f, a1 = 0.f;
    const float* cb = clip + (size_t)b * (256 * 512);
    int i = 0;
    for (; i + 4 <= cnt; i += 4) {
        const int l0 = s_idx[i], l1 = s_idx[i + 1], l2 = s_idx[i + 2], l3 = s_idx[i + 3];
        const float w0 = s_w[i], w1 = s_w[i + 1], w2 = s_w[i + 2], w3 = s_w[i + 3];
        const float2 v0 = *(const float2*)&cb[l0 * 512 + 2 * t];
        const float2 v1 = *(const float2*)&cb[l1 * 512 + 2 * t];
        const float2 v2 = *(const float2*)&cb[l2 * 512 + 2 * t];
        const float2 v3 = *(const float2*)&cb[l3 * 512 + 2 * t];
        a0 += w0 * v0.x + w1 * v1.x + w2 * v2.x + w3 * v3.x;
        a1 += w0 * v0.y + w1 * v1.y + w2 * v2.y + w3 * v3.y;
    }
    for (; i < cnt; ++i) {
        const float2 vv = *(const float2*)&cb[s_idx[i] * 512 + 2 * t];
        a0 += s_w[i] * vv.x;
        a1 += s_w[i] * vv.y;
    }
    float2 o; o.x = a0; o.y = a1;
    *(float2*)&att_res[(size_t)b * 512 + 2 * t] = o;
}

extern "C" void kernel_launch(void* const* d_in, const int* in_sizes, int n_in,
                              void* d_out, int out_size, void* d_ws, size_t ws_size,
                              hipStream_t stream) {
    typedef const float* cf;
    cf xt      = (cf)d_in[0];
    cf video   = (cf)d_in[1];
    cf event   = (cf)d_in[2];
    cf clip    = (cf)d_in[3];
    const int* mask = (const int*)d_in[4];
    cf state_h = (cf)d_in[5];
    cf state_c = (cf)d_in[6];
    cf w_ih0 = (cf)d_in[7],  w_hh0 = (cf)d_in[8],  b_ih0 = (cf)d_in[9],  b_hh0 = (cf)d_in[10];
    cf w_ih1 = (cf)d_in[11], w_hh1 = (cf)d_in[12], b_ih1 = (cf)d_in[13], b_hh1 = (cf)d_in[14];
    cf w_ih2 = (cf)d_in[15], w_hh2 = (cf)d_in[16], b_ih2 = (cf)d_in[17], b_hh2 = (cf)d_in[18];
    cf wc = (cf)d_in[19], bc = (cf)d_in[20];
    cf wh = (cf)d_in[21], bh = (cf)d_in[22];
    cf wa = (cf)d_in[23], ba = (cf)d_in[24];

    float* out = (float*)d_out;
    const int BH = 512 * 512;
    float* new_h = out + BH;       // [3,B,H]
    float* new_c = out + 4 * BH;   // [3,B,H]

    unsigned short* att = (unsigned short*)d_ws;                    // 32 MB bf16
    float* att_res      = (float*)((char*)d_ws + (32u << 20));      // 1 MB

    // K1: layer0 (gemm+cell) || att1, concurrent in one launch
    k1_fused<<<1280, 256, 0, stream>>>(
        xt, video, state_h + 2 * BH, state_h,
        w_ih0, w_hh0, b_ih0, b_hh0,
        state_c, new_h, new_c,
        clip, wc, bc, att);

    // K2: layer1 gemm+cell  (A = [event | h0 | sh1])
    gate_layer<<<512, 128, 0, stream>>>(
        event, new_h, state_h + BH, 512, 512, 512,
        w_ih1, w_hh1, b_ih1, b_hh1,
        state_c + BH, new_h + BH, new_c + BH, nullptr, 1536);

    // K3: attention stage 2 (needs h1)
    att2_kernel<<<512, 256, 0, stream>>>(att, new_h + BH, wh, bh, wa, ba, clip, mask, att_res);

    // K4: layer2 gemm+cell (A = [att_res | h1 | sh2]); h2 dual-written to out[0:BH]
    gate_layer<<<512, 128, 0, stream>>>(
        att_res, new_h + BH, state_h + 2 * BH, 512, 512, 512,
        w_ih2, w_hh2, b_ih2, b_hh2,
        state_c + 2 * BH, new_h + 2 * BH, new_c + 2 * BH, out, 1536);
}

// Round 4
// 730.354 us; speedup vs baseline: 1.2342x; 1.1153x over previous
//
#include <hip/hip_runtime.h>
#include <math.h>

typedef __attribute__((ext_vector_type(8))) short bf16x8;  // 8 bf16 = 4 VGPR
typedef __attribute__((ext_vector_type(4))) float f32x4;   // MFMA acc

constexpr int LST = 72;    // B-tile LDS row stride (shorts): 144 B
constexpr int AST = 520;   // att1 A-tile LDS row stride (shorts): 1040 B (bank step 4 -> 2-way max)

__device__ __forceinline__ unsigned short f2b(float f) {
    union { float f; unsigned int i; } c; c.f = f;
    unsigned int i = c.i;
    return (unsigned short)((i + 0x7fffu + ((i >> 16) & 1u)) >> 16);  // RNE
}
__device__ __forceinline__ void unpack2(unsigned int v, float& lo, float& hi) {
    union { unsigned int i; float f; } c0, c1;
    c0.i = v << 16; c1.i = v & 0xffff0000u;
    lo = c0.f; hi = c1.f;
}
__device__ __forceinline__ uint2 pack4(float4 v) {
    uint2 pk;
    pk.x = (unsigned int)f2b(v.x) | ((unsigned int)f2b(v.y) << 16);
    pk.y = (unsigned int)f2b(v.z) | ((unsigned int)f2b(v.w) << 16);
    return pk;
}
__device__ __forceinline__ float sigf(float x) { return 1.f / (1.f + __expf(-x)); }
__device__ __forceinline__ float tanhfast(float x) { return 1.f - 2.f / (1.f + __expf(2.f * x)); }

// ---------------- gate GEMM + fused LSTM cell ----------------
// gates = [A-pieces]@[W-pieces]^T + b_ih + b_hh, gate-interleaved N-mapping:
// block covers j0..j0+16 for all 4 gates; lane holds (i,f,g,o) of same (b,j).
template<int NT>
__device__ __forceinline__ void gate_body(
    int bx, int t, unsigned short* Al, unsigned short* Bl,
    const float* __restrict__ A0, const float* __restrict__ A1,
    const float* __restrict__ A2, const float* __restrict__ A3,
    int as0, int as1, int as2, int as3,
    const float* __restrict__ B0, const float* __restrict__ B1,
    const float* __restrict__ B2, const float* __restrict__ B3,
    int bs0, int bs1, int bs2, int bs3,
    const float* __restrict__ b_ih, const float* __restrict__ b_hh,
    const float* __restrict__ c_prev, float* __restrict__ h_out,
    float* __restrict__ c_out, float* __restrict__ h_dup, int K)
{
    constexpr int BM = NT / 4;          // rows per block
    constexpr int MBLK = 512 / BM;
    constexpr int NA = BM * 16 / NT;    // A float4-chunks per thread
    constexpr int NB = 1024 / NT;       // B float4-chunks per thread
    const int mb = bx % MBLK, jb = bx / MBLK;
    const int m0 = mb * BM, j0 = jb * 16;
    const int w = t >> 6, lane = t & 63;
    const int col = lane & 15, hi = lane >> 4;

    f32x4 acc[4];
#pragma unroll
    for (int g = 0; g < 4; ++g)
#pragma unroll
        for (int r = 0; r < 4; ++r) acc[g][r] = 0.f;

    for (int kt = 0; kt < K; kt += 64) {
        const int p = kt >> 9, kin = kt & 511;
        const float* ap = (p == 0) ? A0 : (p == 1) ? A1 : (p == 2) ? A2 : A3;
        const int astr   = (p == 0) ? as0 : (p == 1) ? as1 : (p == 2) ? as2 : as3;
        const float* bp = (p == 0) ? B0 : (p == 1) ? B1 : (p == 2) ? B2 : B3;
        const int bstr   = (p == 0) ? bs0 : (p == 1) ? bs1 : (p == 2) ? bs2 : bs3;
        float4 ta[NA], tb[NB];
#pragma unroll
        for (int k = 0; k < NA; ++k) {
            const int c = t + k * NT, row = c >> 4, q = c & 15;
            ta[k] = *(const float4*)(ap + (astr ? (size_t)(m0 + row) * astr : 0) + kin + q * 4);
        }
#pragma unroll
        for (int k = 0; k < NB; ++k) {
            const int c = t + k * NT, row = c >> 4, q = c & 15;
            const int brow = (row >> 4) * 512 + j0 + (row & 15);
            tb[k] = *(const float4*)(bp + (size_t)brow * bstr + kin + q * 4);
        }
        __syncthreads();   // previous tile's LDS reads done
#pragma unroll
        for (int k = 0; k < NA; ++k) {
            const int c = t + k * NT, row = c >> 4, q = c & 15;
            *(uint2*)&Al[row * LST + q * 4] = pack4(ta[k]);
        }
#pragma unroll
        for (int k = 0; k < NB; ++k) {
            const int c = t + k * NT, row = c >> 4, q = c & 15;
            *(uint2*)&Bl[row * LST + q * 4] = pack4(tb[k]);
        }
        __syncthreads();
#pragma unroll
        for (int sub = 0; sub < 2; ++sub) {
            const int ko = sub * 32 + hi * 8;
            const bf16x8 af = *(const bf16x8*)&Al[(w * 16 + col) * LST + ko];
#pragma unroll
            for (int g = 0; g < 4; ++g) {
                const bf16x8 bfr = *(const bf16x8*)&Bl[(g * 16 + col) * LST + ko];
                acc[g] = __builtin_amdgcn_mfma_f32_16x16x32_bf16(af, bfr, acc[g], 0, 0, 0);
            }
        }
    }
    // epilogue: LSTM cell per lane
    const int j = j0 + col;
    const float bi = b_ih[j]        + b_hh[j];
    const float bf = b_ih[512 + j]  + b_hh[512 + j];
    const float bg = b_ih[1024 + j] + b_hh[1024 + j];
    const float bo = b_ih[1536 + j] + b_hh[1536 + j];
#pragma unroll
    for (int r = 0; r < 4; ++r) {
        const int bidx = m0 + w * 16 + hi * 4 + r;
        const size_t off = (size_t)bidx * 512 + j;
        const float gi = acc[0][r] + bi, gf = acc[1][r] + bf;
        const float gg = acc[2][r] + bg, go = acc[3][r] + bo;
        const float c = c_prev[off];
        const float cn = sigf(gf) * c + sigf(gi) * tanhfast(gg);
        const float hn = sigf(go) * tanhfast(cn);
        h_out[off] = hn;
        c_out[off] = cn;
        if (h_dup) h_dup[off] = hn;
    }
}

// ---------------- att1 v2: 32-row block, whole-K LDS-resident A, mask-skip ----------------
__device__ __forceinline__ void att1_body(
    int mb, int t, unsigned short* Ab, unsigned short* Bt, int* s_act,
    const float* __restrict__ clip, const float* __restrict__ wc,
    const float* __restrict__ bc, const int* __restrict__ mask,
    unsigned short* __restrict__ att)
{
    const int m0 = mb * 32;             // linear row = b*256 + l
    if (t < 32) s_act[t] = mask[m0 + t];
    __syncthreads();

    // phase 1: stage active rows (32 x 512 f32 -> bf16), batched loads
    float4 tmp[16];
#pragma unroll
    for (int k = 0; k < 16; ++k) {
        const int c = t + (k << 8), row = c >> 7, q = c & 127;
        if (s_act[row]) tmp[k] = *(const float4*)(clip + (size_t)(m0 + row) * 512 + q * 4);
    }
#pragma unroll
    for (int k = 0; k < 16; ++k) {
        const int c = t + (k << 8), row = c >> 7, q = c & 127;
        if (s_act[row]) *(uint2*)&Ab[row * AST + q * 4] = pack4(tmp[k]);
    }

    const int w = t >> 6, lane = t & 63;
    const int col = lane & 15, hi = lane >> 4;
    f32x4 acc[2][2];
#pragma unroll
    for (int i = 0; i < 2; ++i)
#pragma unroll
        for (int j = 0; j < 2; ++j)
#pragma unroll
            for (int r = 0; r < 4; ++r) acc[i][j][r] = 0.f;

    for (int kt = 0; kt < 8; ++kt) {
        const int k0 = kt * 64;
        float4 tb[8];
#pragma unroll
        for (int k = 0; k < 8; ++k) {   // wc K-tile (L2-hot), issued before barrier
            const int c = t + (k << 8), row = c >> 4, q = c & 15;
            tb[k] = *(const float4*)(wc + (size_t)row * 512 + k0 + q * 4);
        }
        __syncthreads();   // prev tile's Bt reads done; (kt=0) phase-1 Ab visible
#pragma unroll
        for (int k = 0; k < 8; ++k) {
            const int c = t + (k << 8), row = c >> 4, q = c & 15;
            *(uint2*)&Bt[row * LST + q * 4] = pack4(tb[k]);
        }
        __syncthreads();
#pragma unroll
        for (int sub = 0; sub < 2; ++sub) {
            const int ko = sub * 32 + hi * 8;
            bf16x8 af[2], bfr[2];
            af[0] = *(const bf16x8*)&Ab[col * AST + k0 + ko];
            af[1] = *(const bf16x8*)&Ab[(16 + col) * AST + k0 + ko];
            bfr[0] = *(const bf16x8*)&Bt[(w * 32 + col) * LST + ko];
            bfr[1] = *(const bf16x8*)&Bt[(w * 32 + 16 + col) * LST + ko];
#pragma unroll
            for (int i = 0; i < 2; ++i)
#pragma unroll
                for (int j = 0; j < 2; ++j)
                    acc[i][j] = __builtin_amdgcn_mfma_f32_16x16x32_bf16(af[i], bfr[j], acc[i][j], 0, 0, 0);
        }
    }
#pragma unroll
    for (int i = 0; i < 2; ++i)
#pragma unroll
        for (int j = 0; j < 2; ++j) {
            const int n = w * 32 + j * 16 + col;
            const float bias = bc[n];
#pragma unroll
            for (int r = 0; r < 4; ++r) {
                const int m = i * 16 + hi * 4 + r;
                if (s_act[m])
                    att[(size_t)(m0 + m) * 128 + n] = f2b(acc[i][j][r] + bias);
            }
        }
}

// K1: blocks 0..255 = layer0 gemm+cell; blocks 256..4351 = att1 v2
__global__ __launch_bounds__(256, 2)
void k1_fused(const float* xt, const float* video, const float* sh2, const float* sh0,
              const float* w_ih0, const float* w_hh0, const float* b_ih0, const float* b_hh0,
              const float* c_prev0, float* h_out0, float* c_out0,
              const float* clip, const float* wc, const float* bc,
              const int* mask, unsigned short* att)
{
    __shared__ unsigned short Ab[32 * AST];   // 33280 B (gate path uses first 64*72)
    __shared__ unsigned short Bt[128 * LST];  // 18432 B
    __shared__ int s_act[32];
    if (blockIdx.x < 256) {
        gate_body<256>(blockIdx.x, threadIdx.x, Ab, Bt,
                       xt, video, sh2, sh0, 512, 0, 512, 512,
                       w_ih0, w_ih0 + 512, w_ih0 + 1024, w_hh0, 1536, 1536, 1536, 512,
                       b_ih0, b_hh0, c_prev0, h_out0, c_out0, nullptr, 2048);
    } else {
        att1_body(blockIdx.x - 256, threadIdx.x, Ab, Bt, s_act, clip, wc, bc, mask, att);
    }
}

__global__ __launch_bounds__(128, 4)
void gate_layer(const float* A0, const float* A1, const float* A2,
                int as0, int as1, int as2,
                const float* w_ih, const float* w_hh,
                const float* b_ih, const float* b_hh,
                const float* c_prev, float* h_out, float* c_out, float* h_dup, int K)
{
    __shared__ unsigned short Al[32 * LST];
    __shared__ unsigned short Bl[64 * LST];
    gate_body<128>(blockIdx.x, threadIdx.x, Al, Bl,
                   A0, A1, A2, nullptr, as0, as1, as2, 0,
                   w_ih, w_ih + 512, w_hh, nullptr, 1024, 1024, 512, 0,
                   b_ih, b_hh, c_prev, h_out, c_out, h_dup, K);
}

// ---------------- att2: scores + masked softmax + weighted clip sum ----------------
__global__ __launch_bounds__(256)
void att2_kernel(const unsigned short* __restrict__ att, const float* __restrict__ h1,
                 const float* __restrict__ wh, const float* __restrict__ bh,
                 const float* __restrict__ wa, const float* __restrict__ ba,
                 const float* __restrict__ clip, const int* __restrict__ mask,
                 float* __restrict__ att_res)
{
    __shared__ float s_h1[512];
    __shared__ float s_atth[128];
    __shared__ float s_part[256];
    __shared__ float s_wa[128];
    __shared__ float s_sc[256];
    __shared__ float s_red[8];
    __shared__ float s_w[256];
    __shared__ int s_idx[256];
    __shared__ int s_cnt;
    const int b = blockIdx.x, t = threadIdx.x;
    if (t == 0) s_cnt = 0;
    const int act = mask[(size_t)b * 256 + t];

    s_h1[t]       = h1[(size_t)b * 512 + t];
    s_h1[256 + t] = h1[(size_t)b * 512 + 256 + t];
    if (t < 128) s_wa[t] = wa[t];
    __syncthreads();

    {   // att_h partials
        const int a = t & 127, half = t >> 7;
        const float4* wr4 = (const float4*)(wh + (size_t)a * 512 + half * 256);
        const float* hh = s_h1 + half * 256;
        float s = 0.f;
#pragma unroll 4
        for (int k4 = 0; k4 < 64; ++k4) {
            const float4 vv = wr4[k4];
            const float* hp = hh + k4 * 4;
            s += vv.x * hp[0] + vv.y * hp[1] + vv.z * hp[2] + vv.w * hp[3];
        }
        s_part[t] = s;
    }
    __syncthreads();
    if (t < 128) s_atth[t] = s_part[t] + s_part[128 + t] + bh[t];
    __syncthreads();

    {   // score for l = t (garbage for inactive t -- masked below)
        const uint4* ar4 = (const uint4*)(att + ((size_t)b * 256 + t) * 128);
        float s = ba[0];
#pragma unroll 4
        for (int k8 = 0; k8 < 16; ++k8) {
            const uint4 vv = ar4[k8];
            float v0, v1, v2, v3, v4, v5, v6, v7;
            unpack2(vv.x, v0, v1); unpack2(vv.y, v2, v3);
            unpack2(vv.z, v4, v5); unpack2(vv.w, v6, v7);
            const int a0 = k8 * 8;
            s += s_wa[a0 + 0] * tanhfast(v0 + s_atth[a0 + 0]);
            s += s_wa[a0 + 1] * tanhfast(v1 + s_atth[a0 + 1]);
            s += s_wa[a0 + 2] * tanhfast(v2 + s_atth[a0 + 2]);
            s += s_wa[a0 + 3] * tanhfast(v3 + s_atth[a0 + 3]);
            s += s_wa[a0 + 4] * tanhfast(v4 + s_atth[a0 + 4]);
            s += s_wa[a0 + 5] * tanhfast(v5 + s_atth[a0 + 5]);
            s += s_wa[a0 + 6] * tanhfast(v6 + s_atth[a0 + 6]);
            s += s_wa[a0 + 7] * tanhfast(v7 + s_atth[a0 + 7]);
        }
        s_sc[t] = s;
    }
    __syncthreads();

    float v = act ? s_sc[t] : -3.4e38f;   // mask BEFORE max (garbage rows)
    for (int off = 32; off > 0; off >>= 1) v = fmaxf(v, __shfl_down(v, off));
    if ((t & 63) == 0) s_red[t >> 6] = v;
    __syncthreads();
    if (t == 0) s_red[4] = fmaxf(fmaxf(s_red[0], s_red[1]), fmaxf(s_red[2], s_red[3]));
    __syncthreads();
    const float mx = s_red[4];
    const float e = act ? __expf(s_sc[t] - mx) : 0.f;
    float sv = e;
    for (int off = 32; off > 0; off >>= 1) sv += __shfl_down(sv, off);
    if ((t & 63) == 0) s_red[t >> 6] = sv;
    __syncthreads();
    if (t == 0) s_red[5] = s_red[0] + s_red[1] + s_red[2] + s_red[3];
    __syncthreads();
    const float wgt = e / s_red[5];
    if (wgt != 0.f) {   // compact active l's (sum is order-free)
        const int pos = atomicAdd(&s_cnt, 1);
        s_idx[pos] = t;
        s_w[pos] = wgt;
    }
    __syncthreads();
    const int cnt = s_cnt;

    float a0 = 0.f, a1 = 0.f;
    const float* cb = clip + (size_t)b * (256 * 512);
    int i = 0;
    for (; i + 8 <= cnt; i += 8) {
        float2 vv[8]; float ww[8];
#pragma unroll
        for (int u = 0; u < 8; ++u) {
            vv[u] = *(const float2*)&cb[s_idx[i + u] * 512 + 2 * t];
            ww[u] = s_w[i + u];
        }
#pragma unroll
        for (int u = 0; u < 8; ++u) { a0 += ww[u] * vv[u].x; a1 += ww[u] * vv[u].y; }
    }
    for (; i < cnt; ++i) {
        const float2 vv = *(const float2*)&cb[s_idx[i] * 512 + 2 * t];
        a0 += s_w[i] * vv.x;
        a1 += s_w[i] * vv.y;
    }
    float2 o; o.x = a0; o.y = a1;
    *(float2*)&att_res[(size_t)b * 512 + 2 * t] = o;
}

extern "C" void kernel_launch(void* const* d_in, const int* in_sizes, int n_in,
                              void* d_out, int out_size, void* d_ws, size_t ws_size,
                              hipStream_t stream) {
    typedef const float* cf;
    cf xt      = (cf)d_in[0];
    cf video   = (cf)d_in[1];
    cf event   = (cf)d_in[2];
    cf clip    = (cf)d_in[3];
    const int* mask = (const int*)d_in[4];
    cf state_h = (cf)d_in[5];
    cf state_c = (cf)d_in[6];
    cf w_ih0 = (cf)d_in[7],  w_hh0 = (cf)d_in[8],  b_ih0 = (cf)d_in[9],  b_hh0 = (cf)d_in[10];
    cf w_ih1 = (cf)d_in[11], w_hh1 = (cf)d_in[12], b_ih1 = (cf)d_in[13], b_hh1 = (cf)d_in[14];
    cf w_ih2 = (cf)d_in[15], w_hh2 = (cf)d_in[16], b_ih2 = (cf)d_in[17], b_hh2 = (cf)d_in[18];
    cf wc = (cf)d_in[19], bc = (cf)d_in[20];
    cf wh = (cf)d_in[21], bh = (cf)d_in[22];
    cf wa = (cf)d_in[23], ba = (cf)d_in[24];

    float* out = (float*)d_out;
    const int BH = 512 * 512;
    float* new_h = out + BH;       // [3,B,H]
    float* new_c = out + 4 * BH;   // [3,B,H]

    unsigned short* att = (unsigned short*)d_ws;                // 32 MB bf16
    float* att_res      = (float*)((char*)d_ws + (32u << 20));  // 1 MB

    // K1: layer0 (gemm+cell, blocks 0-255) || att1 v2 (blocks 256-4351)
    k1_fused<<<4352, 256, 0, stream>>>(
        xt, video, state_h + 2 * BH, state_h,
        w_ih0, w_hh0, b_ih0, b_hh0,
        state_c, new_h, new_c,
        clip, wc, bc, mask, att);

    // K2: layer1 gemm+cell  (A = [event | h0 | sh1])
    gate_layer<<<512, 128, 0, stream>>>(
        event, new_h, state_h + BH, 512, 512, 512,
        w_ih1, w_hh1, b_ih1, b_hh1,
        state_c + BH, new_h + BH, new_c + BH, nullptr, 1536);

    // K3: attention stage 2 (needs h1 + att)
    att2_kernel<<<512, 256, 0, stream>>>(att, new_h + BH, wh, bh, wa, ba, clip, mask, att_res);

    // K4: layer2 gemm+cell (A = [att_res | h1 | sh2]); h2 dual-written to out[0:BH]
    gate_layer<<<512, 128, 0, stream>>>(
        att_res, new_h + BH, state_h + 2 * BH, 512, 512, 512,
        w_ih2, w_hh2, b_ih2, b_hh2,
        state_c + 2 * BH, new_h + 2 * BH, new_c + 2 * BH, out, 1536);
}